// Round 10
// baseline (379.363 us; speedup 1.0000x reference)
//
#include <hip/hip_runtime.h>

#define N_NODES 100000
#define N_EDGES 600000
#define NT1 1563    // k1 node tiles of 64
#define NT2 9375    // k2 edge tiles of 64 (600000 = 9375*64 exactly)
#define NB  1563    // sort buckets: src>>6 (64-node / 32KB P-window each)
#define LDH 136     // padded row stride (f16 elems), 16B-aligned rows
typedef _Float16 f16x8 __attribute__((ext_vector_type(8)));
typedef __attribute__((ext_vector_type(4))) float f32x4;

__device__ __forceinline__ float elu_f(float v) {
    return v > 0.0f ? v : (__expf(v) - 1.0f);
}

// ---- mode detection helper (int64 vs int32 edge_index), proven pattern ----
#define DETECT_MODE(SFLAG, MODE)                                        \
    if (threadIdx.x < 64) {                                             \
        unsigned v_ = ((const unsigned*)eiv)[2 * threadIdx.x + 1];      \
        unsigned long long bm_ = __ballot(v_ == 0u);                    \
        if (threadIdx.x == 0) SFLAG = (bm_ == ~0ull) ? 1 : 0;           \
    }                                                                   \
    __syncthreads();                                                    \
    const int MODE = SFLAG;

// k0: build W1f (W1 in MFMA-fragment order, 64KB) + zero sort counters.
extern "C" __global__ __launch_bounds__(256)
void k0_w1f(const float* __restrict__ W1, _Float16* __restrict__ W1f,
            int* __restrict__ cnt) {
    const int t = threadIdx.x;
    const int id = blockIdx.x * 256 + t;   // 0..4095
    if (id < NB) cnt[id] = 0;
    const int lane = id & 63, f = id >> 6;
    const int ks = f & 3, c = (f >> 2) & 1, half = (f >> 3) & 1, w = f >> 4;
    const int ln = lane & 15, kg = lane >> 4;
    const int col = w * 32 + c * 16 + ln;
    f16x8 v;
#pragma unroll
    for (int j = 0; j < 8; ++j)
        v[j] = (_Float16)W1[(half * 128 + ks * 32 + kg * 8 + j) * 128 + col];
    *(f16x8*)(W1f + (size_t)id * 8) = v;
}

// kh: histogram of src-bucket occupancy.
extern "C" __global__ __launch_bounds__(256)
void k_hist(const void* __restrict__ eiv, int* __restrict__ cnt) {
    __shared__ int sFlag;
    DETECT_MODE(sFlag, mode64)
    const int step = gridDim.x * blockDim.x;
    for (int e = blockIdx.x * blockDim.x + threadIdx.x; e < N_EDGES; e += step) {
        int se = mode64 ? (int)((const long long*)eiv)[e] : ((const int*)eiv)[e];
        atomicAdd(&cnt[se >> 6], 1);
    }
}

// ks: exclusive scan of cnt -> off (single block).
extern "C" __global__ __launch_bounds__(256)
void k_scan(const int* __restrict__ cnt, int* __restrict__ off) {
    __shared__ int sSum[256];
    const int t = threadIdx.x;
    const int base = t * 7;              // 256*7 = 1792 >= NB
    int loc[7]; int s = 0;
#pragma unroll
    for (int i = 0; i < 7; ++i) {
        int idx = base + i;
        int v = (idx < NB) ? cnt[idx] : 0;
        loc[i] = s; s += v;
    }
    sSum[t] = s; __syncthreads();
    for (int d = 1; d < 256; d <<= 1) {
        int v = (t >= d) ? sSum[t - d] : 0;
        __syncthreads();
        sSum[t] += v;
        __syncthreads();
    }
    int pre = sSum[t] - s;               // exclusive prefix of this chunk
#pragma unroll
    for (int i = 0; i < 7; ++i)
        if (base + i < NB) off[base + i] = pre + loc[i];
}

// kc: scatter edges into src-sorted order; emit packed int2 indices + the
// inverse permutation for the output write.
extern "C" __global__ __launch_bounds__(256)
void k_scatter(const void* __restrict__ eiv, int* __restrict__ off,
               int2* __restrict__ ES, int* __restrict__ orig) {
    __shared__ int sFlag;
    DETECT_MODE(sFlag, mode64)
    const int step = gridDim.x * blockDim.x;
    for (int e = blockIdx.x * blockDim.x + threadIdx.x; e < N_EDGES; e += step) {
        int se, ge;
        if (mode64) {
            se = (int)((const long long*)eiv)[e];
            ge = (int)((const long long*)eiv)[N_EDGES + e];
        } else {
            se = ((const int*)eiv)[e];
            ge = ((const int*)eiv)[N_EDGES + e];
        }
        int pos = atomicAdd(&off[se >> 6], 1);
        ES[pos] = make_int2(se, ge);
        orig[pos] = e;
    }
}

// k1: byte-identical to r8 (steady-state ~35-40us).
extern "C" __global__ __launch_bounds__(256, 3)
void k1_node_linear(const float* __restrict__ x, const _Float16* __restrict__ W1f,
                    _Float16* __restrict__ P) {
    __shared__ __align__(16) _Float16 sX[64 * LDH];   // 17.4 KB

    const int t = threadIdx.x;
    const int w = t >> 6, lane = t & 63;
    const int ln = lane & 15, kg = lane >> 4;
    const int le = t >> 2;        // staging/store row 0..63
    const int q  = t & 3;         // 32-col chunk 0..3

    f16x8 bf[2][2][4];
#pragma unroll
    for (int half = 0; half < 2; ++half)
#pragma unroll
        for (int c = 0; c < 2; ++c)
#pragma unroll
            for (int ks = 0; ks < 4; ++ks)
                bf[half][c][ks] = *(const f16x8*)(
                    W1f + (size_t)((w * 16 + half * 8 + c * 4 + ks) * 64 + lane) * 8);

    for (int tile = blockIdx.x; tile < NT1; tile += gridDim.x) {
        const int n0 = tile * 64;
        __syncthreads();   // previous tile's epilogue reads of sX done

        {
            int n = n0 + le;
#pragma unroll
            for (int i = 0; i < 4; ++i) {
                float4 a0 = make_float4(0.f, 0.f, 0.f, 0.f), a1 = a0;
                if (n < N_NODES) {
                    const float* p = x + (size_t)n * 128 + q * 32 + i * 8;
                    a0 = *(const float4*)p; a1 = *(const float4*)(p + 4);
                }
                f16x8 vh;
                vh[0] = (_Float16)a0.x; vh[1] = (_Float16)a0.y;
                vh[2] = (_Float16)a0.z; vh[3] = (_Float16)a0.w;
                vh[4] = (_Float16)a1.x; vh[5] = (_Float16)a1.y;
                vh[6] = (_Float16)a1.z; vh[7] = (_Float16)a1.w;
                *(f16x8*)(&sX[le * LDH + q * 32 + i * 8]) = vh;
            }
        }
        __syncthreads();

        f32x4 acc[2][4][2];
#pragma unroll
        for (int half = 0; half < 2; ++half)
#pragma unroll
            for (int rt = 0; rt < 4; ++rt)
#pragma unroll
                for (int c = 0; c < 2; ++c) acc[half][rt][c] = (f32x4){0.f, 0.f, 0.f, 0.f};

#pragma unroll
        for (int ks = 0; ks < 4; ++ks) {
#pragma unroll
            for (int rt = 0; rt < 4; ++rt) {
                f16x8 a = *(const f16x8*)(&sX[(rt * 16 + ln) * LDH + ks * 32 + kg * 8]);
#pragma unroll
                for (int half = 0; half < 2; ++half)
#pragma unroll
                    for (int c = 0; c < 2; ++c)
                        acc[half][rt][c] = __builtin_amdgcn_mfma_f32_16x16x32_f16(
                            a, bf[half][c][ks], acc[half][rt][c], 0, 0, 0);
            }
        }

#pragma unroll
        for (int half = 0; half < 2; ++half) {
            __syncthreads();
#pragma unroll
            for (int rt = 0; rt < 4; ++rt)
#pragma unroll
                for (int c = 0; c < 2; ++c) {
                    int col = w * 32 + c * 16 + ln;
#pragma unroll
                    for (int reg = 0; reg < 4; ++reg) {
                        int row = rt * 16 + kg * 4 + reg;   // C-layout [m89/m91]
                        sX[row * LDH + col] = (_Float16)acc[half][rt][c][reg];
                    }
                }
            __syncthreads();
            int n = n0 + le;
            if (n < N_NODES) {
                _Float16* dst = P + (size_t)n * 256 + half * 128 + q * 32;
                const _Float16* srcp = &sX[le * LDH + q * 32];
#pragma unroll
                for (int i = 0; i < 4; ++i)
                    *(f16x8*)(dst + i * 8) = *(const f16x8*)(srcp + i * 8);
            }
        }
    }
}

// k2: r8's proven 85us body (depth-1 register gather, 1 barrier/tile, 3
// blocks/CU), now consuming SRC-SORTED edges: src gathers hit a sliding
// 32KB window (a node's ~6 edges are adjacent -> same tile/XCD), indices
// arrive as packed int2 (dual-mode logic gone), out is a 4B scatter via orig.
extern "C" __global__ __launch_bounds__(256, 3)
void k2_edge_mlp(const _Float16* __restrict__ P, const int2* __restrict__ ES,
                 const int* __restrict__ orig,
                 const float* __restrict__ b1, const float* __restrict__ W2,
                 const float* __restrict__ b2, const float* __restrict__ W3,
                 const float* __restrict__ b3, float* __restrict__ out) {
    __shared__ __align__(16) _Float16 sH[2][64 * LDH];   // 34.8 KB
    __shared__ float sPart[2][4][64];                    // 2 KB

    const int t = threadIdx.x;
    const int w = t >> 6, lane = t & 63;
    const int ln = lane & 15, kg = lane >> 4;
    const int row = t >> 2;          // staging row 0..63
    const int kc0 = (t & 3) * 4;     // staging k-chunk base (of 16 chunks/row)
    const float b3v = b3[0];
    const int stride = gridDim.x;

    f16x8 b1f[4];
#pragma unroll
    for (int i = 0; i < 4; ++i)
#pragma unroll
        for (int j = 0; j < 8; ++j) b1f[i][j] = (_Float16)b1[(kc0 + i) * 8 + j];

    float w3v[2], b2v[2];
#pragma unroll
    for (int c = 0; c < 2; ++c) {
        int col = w * 32 + c * 16 + ln;
        w3v[c] = W3[col]; b2v[c] = b2[col];
    }

    f16x8 bfw[2][4];
#pragma unroll
    for (int c = 0; c < 2; ++c) {
        const int n = w * 32 + c * 16 + ln;
#pragma unroll
        for (int ks = 0; ks < 4; ++ks) {
            f16x8 v;
#pragma unroll
            for (int j = 0; j < 8; ++j) {
                int k = ks * 32 + kg * 8 + j;
                v[j] = (_Float16)W2[k * 128 + n];
            }
            bfw[c][ks] = v;
        }
    }

    const int tile0 = blockIdx.x;   // 768 <= NT2 always

    int se_nx, ge_nx;
    {
        int2 eg = ES[tile0 * 64 + row];
        const _Float16* pa = P + (size_t)eg.x * 256 + kc0 * 8;
        const _Float16* pb = P + (size_t)eg.y * 256 + 128 + kc0 * 8;
        f16x8 Ga[4], Gb[4];
#pragma unroll
        for (int i = 0; i < 4; ++i) {
            Ga[i] = *(const f16x8*)(pa + i * 8);
            Gb[i] = *(const f16x8*)(pb + i * 8);
        }
#pragma unroll
        for (int i = 0; i < 4; ++i) {
            f16x8 s = Ga[i] + Gb[i] + b1f[i];   // packed f16 adds
            f16x8 vh;
#pragma unroll
            for (int j = 0; j < 8; ++j) {
                _Float16 sv = s[j];
                vh[j] = (sv > (_Float16)0) ? sv
                        : (_Float16)(__expf((float)sv) - 1.0f);
            }
            *(f16x8*)(&sH[0][row * LDH + (kc0 + i) * 8]) = vh;
        }
    }
    {
        int t1 = tile0 + stride;
        int t1c = (t1 < NT2) ? t1 : tile0;
        int2 eg = ES[t1c * 64 + row];
        se_nx = eg.x; ge_nx = eg.y;
    }
    __syncthreads();   // sH[0] ready

    int p = 0;
    int prevE0 = -1;
    for (int tile = tile0; tile < NT2; tile += stride) {
        const int nt = tile + stride;
        const int ntc = (nt < NT2) ? nt : tile;

        // (1) Issue gathers for tile nt.
        const _Float16* pa = P + (size_t)se_nx * 256 + kc0 * 8;
        const _Float16* pb = P + (size_t)ge_nx * 256 + 128 + kc0 * 8;
        f16x8 Ga[4], Gb[4];
#pragma unroll
        for (int i = 0; i < 4; ++i) {
            Ga[i] = *(const f16x8*)(pa + i * 8);
            Gb[i] = *(const f16x8*)(pb + i * 8);
        }

        // (1b) Indices for tile nt+stride.
        {
            int n2 = nt + stride;
            int n2c = (n2 < NT2) ? n2 : ntc;
            int2 eg = ES[n2c * 64 + row];
            se_nx = eg.x; ge_nx = eg.y;
        }

        // (2) Out-write for the previous tile (scatter via inverse perm).
        if (prevE0 >= 0 && t < 64) {
            int o = orig[prevE0 + t];
            out[o] = sPart[p ^ 1][0][t] + sPart[p ^ 1][1][t] +
                     sPart[p ^ 1][2][t] + sPart[p ^ 1][3][t] + b3v;
        }

        // (3) MFMA on sH[p] + fused layer 3 -> sPart[p].
        f32x4 acc[4][2];
#pragma unroll
        for (int rt = 0; rt < 4; ++rt)
#pragma unroll
            for (int c = 0; c < 2; ++c) acc[rt][c] = (f32x4){0.f, 0.f, 0.f, 0.f};

#pragma unroll
        for (int ks = 0; ks < 4; ++ks) {
#pragma unroll
            for (int rt = 0; rt < 4; ++rt) {
                f16x8 a = *(const f16x8*)(&sH[p][(rt * 16 + ln) * LDH + ks * 32 + kg * 8]);
#pragma unroll
                for (int c = 0; c < 2; ++c)
                    acc[rt][c] = __builtin_amdgcn_mfma_f32_16x16x32_f16(a, bfw[c][ks], acc[rt][c], 0, 0, 0);
            }
        }

#pragma unroll
        for (int rt = 0; rt < 4; ++rt) {
            float pr[4] = {0.f, 0.f, 0.f, 0.f};
#pragma unroll
            for (int c = 0; c < 2; ++c) {
#pragma unroll
                for (int reg = 0; reg < 4; ++reg)
                    pr[reg] += elu_f(acc[rt][c][reg] + b2v[c]) * w3v[c];
            }
#pragma unroll
            for (int m = 1; m < 16; m <<= 1)
#pragma unroll
                for (int reg = 0; reg < 4; ++reg) pr[reg] += __shfl_xor(pr[reg], m, 64);
            if (ln == 0) {
#pragma unroll
                for (int reg = 0; reg < 4; ++reg)
                    sPart[p][w][rt * 16 + kg * 4 + reg] = pr[reg];
            }
        }

        // (4) Combine gathered tile nt -> sH[p^1] (packed f16 math).
#pragma unroll
        for (int i = 0; i < 4; ++i) {
            f16x8 s = Ga[i] + Gb[i] + b1f[i];   // v_pk_add_f16
            f16x8 vh;
#pragma unroll
            for (int j = 0; j < 8; ++j) {
                _Float16 sv = s[j];
                vh[j] = (sv > (_Float16)0) ? sv
                        : (_Float16)(__expf((float)sv) - 1.0f);
            }
            *(f16x8*)(&sH[p ^ 1][row * LDH + (kc0 + i) * 8]) = vh;
        }

        prevE0 = tile * 64;
        __syncthreads();   // the ONLY per-tile barrier
        p ^= 1;
    }

    if (prevE0 >= 0 && t < 64) {
        int o = orig[prevE0 + t];
        out[o] = sPart[p ^ 1][0][t] + sPart[p ^ 1][1][t] +
                 sPart[p ^ 1][2][t] + sPart[p ^ 1][3][t] + b3v;
    }
}

extern "C" void kernel_launch(void* const* d_in, const int* in_sizes, int n_in,
                              void* d_out, int out_size, void* d_ws, size_t ws_size,
                              hipStream_t stream) {
    const float* x  = (const float*)d_in[0];
    const void*  ei = d_in[1];
    const float* W1 = (const float*)d_in[2];
    const float* b1 = (const float*)d_in[3];
    const float* W2 = (const float*)d_in[4];
    const float* b2 = (const float*)d_in[5];
    const float* W3 = (const float*)d_in[6];
    const float* b3 = (const float*)d_in[7];
    float* out = (float*)d_out;

    // Workspace layout (all 256B-aligned):
    char* wsp = (char*)d_ws + 256;
    _Float16* P    = (_Float16*)wsp;                   wsp += (size_t)N_NODES * 256 * 2;  // 51.2 MB
    _Float16* W1f  = (_Float16*)wsp;                   wsp += 4096 * 16;                  // 64 KB
    int2*     ES   = (int2*)wsp;                       wsp += (size_t)N_EDGES * 8;        // 4.8 MB
    int*      orig = (int*)wsp;                        wsp += (size_t)N_EDGES * 4;        // 2.4 MB
    int*      cnt  = (int*)wsp;                        wsp += ((NB * 4 + 255) & ~255);    // 6.3 KB
    int*      off  = (int*)wsp;                                                          // 6.3 KB

    k0_w1f<<<16, 256, 0, stream>>>(W1, W1f, cnt);
    k_hist<<<1024, 256, 0, stream>>>(ei, cnt);
    k_scan<<<1, 256, 0, stream>>>(cnt, off);
    k_scatter<<<1024, 256, 0, stream>>>(ei, off, ES, orig);
    k1_node_linear<<<768, 256, 0, stream>>>(x, W1f, P);
    k2_edge_mlp<<<768, 256, 0, stream>>>(P, ES, orig, b1, W2, b2, W3, b3, out);
}

// Round 11
// 277.196 us; speedup vs baseline: 1.3686x; 1.3686x over previous
//
#include <hip/hip_runtime.h>

#define N_NODES 100000
#define N_EDGES 600000
#define NT1 1563    // k1 node tiles of 64
#define NT2 9375    // k2 edge tiles of 64 (600000 = 9375*64 exactly)
#define LDH 136     // padded row stride (f16 elems), 16B-aligned rows
typedef _Float16 f16x8 __attribute__((ext_vector_type(8)));
typedef __attribute__((ext_vector_type(4))) float f32x4;

__device__ __forceinline__ float elu_f(float v) {
    return v > 0.0f ? v : (__expf(v) - 1.0f);
}

// k0: build W1f (W1 in MFMA-fragment order, 64KB) [r8, kept: coalesced k1
// preload] + zero the two ticket counters for this launch iteration.
extern "C" __global__ __launch_bounds__(256)
void k0_w1f(const float* __restrict__ W1, _Float16* __restrict__ W1f,
            int* __restrict__ tks) {
    const int t = threadIdx.x;
    if (blockIdx.x == 0 && t < 2) tks[t] = 0;
    const int id = blockIdx.x * 256 + t;   // 0..4095
    const int lane = id & 63, f = id >> 6;
    const int ks = f & 3, c = (f >> 2) & 1, half = (f >> 3) & 1, w = f >> 4;
    const int ln = lane & 15, kg = lane >> 4;
    const int col = w * 32 + c * 16 + ln;
    f16x8 v;
#pragma unroll
    for (int j = 0; j < 8; ++j)
        v[j] = (_Float16)W1[(half * 128 + ks * 32 + kg * 8 + j) * 128 + col];
    *(f16x8*)(W1f + (size_t)id * 8) = v;
}

// k1: r8 body with TICKET scheduling. Static stride-768 assignment gives 27
// blocks 3 tiles while 741 do 2 -> wall = 3x tile-time (~+48% convoy).
// Tickets balance to +-1 tile. Grab (t0, between B1 and the epilogue
// barriers) and read (after B6) are separated by >=1 barrier on both sides.
extern "C" __global__ __launch_bounds__(256, 3)
void k1_node_linear(const float* __restrict__ x, const _Float16* __restrict__ W1f,
                    _Float16* __restrict__ P, int* __restrict__ tk) {
    __shared__ __align__(16) _Float16 sX[64 * LDH];   // 17.4 KB
    __shared__ int sTk;

    const int t = threadIdx.x;
    const int w = t >> 6, lane = t & 63;
    const int ln = lane & 15, kg = lane >> 4;
    const int le = t >> 2;        // staging/store row 0..63
    const int q  = t & 3;         // 32-col chunk 0..3

    f16x8 bf[2][2][4];
#pragma unroll
    for (int half = 0; half < 2; ++half)
#pragma unroll
        for (int c = 0; c < 2; ++c)
#pragma unroll
            for (int ks = 0; ks < 4; ++ks)
                bf[half][c][ks] = *(const f16x8*)(
                    W1f + (size_t)((w * 16 + half * 8 + c * 4 + ks) * 64 + lane) * 8);

    if (t == 0) sTk = atomicAdd(tk, 1);
    __syncthreads();
    int tile = sTk;

    while (tile < NT1) {
        const int n0 = tile * 64;

        // Stage x tile as f16 (single read of x).
        {
            int n = n0 + le;
#pragma unroll
            for (int i = 0; i < 4; ++i) {
                float4 a0 = make_float4(0.f, 0.f, 0.f, 0.f), a1 = a0;
                if (n < N_NODES) {
                    const float* p = x + (size_t)n * 128 + q * 32 + i * 8;
                    a0 = *(const float4*)p; a1 = *(const float4*)(p + 4);
                }
                f16x8 vh;
                vh[0] = (_Float16)a0.x; vh[1] = (_Float16)a0.y;
                vh[2] = (_Float16)a0.z; vh[3] = (_Float16)a0.w;
                vh[4] = (_Float16)a1.x; vh[5] = (_Float16)a1.y;
                vh[6] = (_Float16)a1.z; vh[7] = (_Float16)a1.w;
                *(f16x8*)(&sX[le * LDH + q * 32 + i * 8]) = vh;
            }
        }
        __syncthreads();   // B1: sX ready

        f32x4 acc[2][4][2];
#pragma unroll
        for (int half = 0; half < 2; ++half)
#pragma unroll
            for (int rt = 0; rt < 4; ++rt)
#pragma unroll
                for (int c = 0; c < 2; ++c) acc[half][rt][c] = (f32x4){0.f, 0.f, 0.f, 0.f};

#pragma unroll
        for (int ks = 0; ks < 4; ++ks) {
#pragma unroll
            for (int rt = 0; rt < 4; ++rt) {
                f16x8 a = *(const f16x8*)(&sX[(rt * 16 + ln) * LDH + ks * 32 + kg * 8]);
#pragma unroll
                for (int half = 0; half < 2; ++half)
#pragma unroll
                    for (int c = 0; c < 2; ++c)
                        acc[half][rt][c] = __builtin_amdgcn_mfma_f32_16x16x32_f16(
                            a, bf[half][c][ks], acc[half][rt][c], 0, 0, 0);
            }
        }

        // Grab next ticket: >=1 barrier after this write before the bottom
        // read; >=1 barrier (epilogue's) before the next iteration's write.
        if (t == 0) sTk = atomicAdd(tk, 1);

        // Epilogue per half: bounce through sX, coalesced f16 stores.
#pragma unroll
        for (int half = 0; half < 2; ++half) {
            __syncthreads();
#pragma unroll
            for (int rt = 0; rt < 4; ++rt)
#pragma unroll
                for (int c = 0; c < 2; ++c) {
                    int col = w * 32 + c * 16 + ln;
#pragma unroll
                    for (int reg = 0; reg < 4; ++reg) {
                        int row = rt * 16 + kg * 4 + reg;   // C-layout [m89/m91]
                        sX[row * LDH + col] = (_Float16)acc[half][rt][c][reg];
                    }
                }
            __syncthreads();
            int n = n0 + le;
            if (n < N_NODES) {
                _Float16* dst = P + (size_t)n * 256 + half * 128 + q * 32;
                const _Float16* srcp = &sX[le * LDH + q * 32];
#pragma unroll
                for (int i = 0; i < 4; ++i)
                    *(f16x8*)(dst + i * 8) = *(const f16x8*)(srcp + i * 8);
            }
        }

        __syncthreads();   // B6: epilogue sX reads done; sTk visible
        tile = sTk;
    }
}

// k2: r8's proven 85us body (depth-1 register gather, 1 barrier/tile, 3
// blocks/CU) with TICKET scheduling: 159/768 blocks did 13 tiles vs 12
// (+5.4% convoy); tickets balance to +-1 and let cache-unlucky blocks take
// fewer tiles. Pipeline chain per tile: grabbed(i) -> idx-loaded(i+1) ->
// gathered(i+2) -> computed(i+3) -> out(i+4). Ticket broadcast uses 2 LDS
// slots indexed by the loop parity p: slot written in iter i (parity p) is
// re-written two barriers later -> no read/write race.
extern "C" __global__ __launch_bounds__(256, 3)
void k2_edge_mlp(const _Float16* __restrict__ P, const void* __restrict__ eiv,
                 const float* __restrict__ b1, const float* __restrict__ W2,
                 const float* __restrict__ b2, const float* __restrict__ W3,
                 const float* __restrict__ b3, float* __restrict__ out,
                 int* __restrict__ tk) {
    __shared__ __align__(16) _Float16 sH[2][64 * LDH];   // 34.8 KB
    __shared__ float sPart[2][4][64];                    // 2 KB
    __shared__ int sFlag;
    __shared__ int sBoot[3];
    __shared__ int sN[2];

    const int t = threadIdx.x;
    const int w = t >> 6, lane = t & 63;
    const int ln = lane & 15, kg = lane >> 4;
    const int row = t >> 2;          // staging row 0..63
    const int kc0 = (t & 3) * 4;     // staging k-chunk base (of 16 chunks/row)
    const float b3v = b3[0];

    if (t < 64) {
        unsigned v = ((const unsigned*)eiv)[2 * t + 1];
        unsigned long long bm = __ballot(v == 0u);
        if (t == 0) sFlag = (bm == ~0ull) ? 1 : 0;
    }
    if (t == 0) {
        sBoot[0] = atomicAdd(tk, 1);
        sBoot[1] = atomicAdd(tk, 1);
        sBoot[2] = atomicAdd(tk, 1);
    }

    f16x8 b1f[4];
#pragma unroll
    for (int i = 0; i < 4; ++i)
#pragma unroll
        for (int j = 0; j < 8; ++j) b1f[i][j] = (_Float16)b1[(kc0 + i) * 8 + j];

    float w3v[2], b2v[2];
#pragma unroll
    for (int c = 0; c < 2; ++c) {
        int col = w * 32 + c * 16 + ln;
        w3v[c] = W3[col]; b2v[c] = b2[col];
    }

    f16x8 bfw[2][4];
#pragma unroll
    for (int c = 0; c < 2; ++c) {
        const int n = w * 32 + c * 16 + ln;
#pragma unroll
        for (int ks = 0; ks < 4; ++ks) {
            f16x8 v;
#pragma unroll
            for (int j = 0; j < 8; ++j) {
                int k = ks * 32 + kg * 8 + j;
                v[j] = (_Float16)W2[k * 128 + n];
            }
            bfw[c][ks] = v;
        }
    }
    __syncthreads();
    const int mode64 = sFlag;
    int tCur = sBoot[0], tNxt = sBoot[1], tIdl = sBoot[2];
    if (tCur >= NT2) return;   // uniform block exit

#define LOAD_IDX(TT, SE, GE) do {                                   \
        int e_ = (TT) * 64 + row;                                   \
        if (mode64) {                                               \
            SE = (int)((const long long*)eiv)[e_];                  \
            GE = (int)((const long long*)eiv)[N_EDGES + e_];        \
        } else {                                                    \
            SE = ((const int*)eiv)[e_];                             \
            GE = ((const int*)eiv)[N_EDGES + e_];                   \
        }                                                           \
    } while (0)

    int se_nx, ge_nx;
    // Prologue: gather+combine tCur directly into sH[0]; idx loads for tNxt.
    {
        int se, ge;
        LOAD_IDX(tCur, se, ge);
        const _Float16* pa = P + (size_t)se * 256 + kc0 * 8;
        const _Float16* pb = P + (size_t)ge * 256 + 128 + kc0 * 8;
        f16x8 Ga[4], Gb[4];
#pragma unroll
        for (int i = 0; i < 4; ++i) {
            Ga[i] = *(const f16x8*)(pa + i * 8);
            Gb[i] = *(const f16x8*)(pb + i * 8);
        }
#pragma unroll
        for (int i = 0; i < 4; ++i) {
            f16x8 s = Ga[i] + Gb[i] + b1f[i];   // packed f16 adds
            f16x8 vh;
#pragma unroll
            for (int j = 0; j < 8; ++j) {
                _Float16 sv = s[j];
                vh[j] = (sv > (_Float16)0) ? sv
                        : (_Float16)(__expf((float)sv) - 1.0f);
            }
            *(f16x8*)(&sH[0][row * LDH + (kc0 + i) * 8]) = vh;
        }
    }
    {
        int tc = (tNxt < NT2) ? tNxt : 0;
        LOAD_IDX(tc, se_nx, ge_nx);
    }
    __syncthreads();   // sH[0] ready; sBoot consumed

    int p = 0;
    int prevE0 = -1;
    while (tCur < NT2) {
        // (0) Grab the tile for 3 iterations ahead.
        if (t == 0) sN[p] = atomicAdd(tk, 1);

        // (1) Issue gathers for tNxt (addresses from last iter's idx loads).
        const _Float16* pa = P + (size_t)se_nx * 256 + kc0 * 8;
        const _Float16* pb = P + (size_t)ge_nx * 256 + 128 + kc0 * 8;
        f16x8 Ga[4], Gb[4];
#pragma unroll
        for (int i = 0; i < 4; ++i) {
            Ga[i] = *(const f16x8*)(pa + i * 8);
            Gb[i] = *(const f16x8*)(pb + i * 8);
        }

        // (1b) Idx loads for tIdl (clamped when past the end).
        {
            int tc = (tIdl < NT2) ? tIdl : 0;
            LOAD_IDX(tc, se_nx, ge_nx);
        }

        // (2) Out-write for the previous tile.
        if (prevE0 >= 0 && t < 64)
            out[prevE0 + t] = sPart[p ^ 1][0][t] + sPart[p ^ 1][1][t] +
                              sPart[p ^ 1][2][t] + sPart[p ^ 1][3][t] + b3v;

        // (3) MFMA on sH[p] + fused layer 3 -> sPart[p].
        f32x4 acc[4][2];
#pragma unroll
        for (int rt = 0; rt < 4; ++rt)
#pragma unroll
            for (int c = 0; c < 2; ++c) acc[rt][c] = (f32x4){0.f, 0.f, 0.f, 0.f};

#pragma unroll
        for (int ks = 0; ks < 4; ++ks) {
#pragma unroll
            for (int rt = 0; rt < 4; ++rt) {
                f16x8 a = *(const f16x8*)(&sH[p][(rt * 16 + ln) * LDH + ks * 32 + kg * 8]);
#pragma unroll
                for (int c = 0; c < 2; ++c)
                    acc[rt][c] = __builtin_amdgcn_mfma_f32_16x16x32_f16(a, bfw[c][ks], acc[rt][c], 0, 0, 0);
            }
        }

#pragma unroll
        for (int rt = 0; rt < 4; ++rt) {
            float pr[4] = {0.f, 0.f, 0.f, 0.f};
#pragma unroll
            for (int c = 0; c < 2; ++c) {
#pragma unroll
                for (int reg = 0; reg < 4; ++reg)
                    pr[reg] += elu_f(acc[rt][c][reg] + b2v[c]) * w3v[c];
            }
#pragma unroll
            for (int m = 1; m < 16; m <<= 1)
#pragma unroll
                for (int reg = 0; reg < 4; ++reg) pr[reg] += __shfl_xor(pr[reg], m, 64);
            if (ln == 0) {
#pragma unroll
                for (int reg = 0; reg < 4; ++reg)
                    sPart[p][w][rt * 16 + kg * 4 + reg] = pr[reg];
            }
        }

        // (4) Combine gathered tile tNxt -> sH[p^1] (packed f16 math).
#pragma unroll
        for (int i = 0; i < 4; ++i) {
            f16x8 s = Ga[i] + Gb[i] + b1f[i];   // v_pk_add_f16
            f16x8 vh;
#pragma unroll
            for (int j = 0; j < 8; ++j) {
                _Float16 sv = s[j];
                vh[j] = (sv > (_Float16)0) ? sv
                        : (_Float16)(__expf((float)sv) - 1.0f);
            }
            *(f16x8*)(&sH[p ^ 1][row * LDH + (kc0 + i) * 8]) = vh;
        }

        prevE0 = tCur * 64;
        __syncthreads();   // the ONLY per-tile barrier; sN[p] now visible
        tCur = tNxt; tNxt = tIdl; tIdl = sN[p];
        p ^= 1;
    }

    if (prevE0 >= 0 && t < 64)
        out[prevE0 + t] = sPart[p ^ 1][0][t] + sPart[p ^ 1][1][t] +
                          sPart[p ^ 1][2][t] + sPart[p ^ 1][3][t] + b3v;
#undef LOAD_IDX
}

extern "C" void kernel_launch(void* const* d_in, const int* in_sizes, int n_in,
                              void* d_out, int out_size, void* d_ws, size_t ws_size,
                              hipStream_t stream) {
    const float* x  = (const float*)d_in[0];
    const void*  ei = d_in[1];
    const float* W1 = (const float*)d_in[2];
    const float* b1 = (const float*)d_in[3];
    const float* W2 = (const float*)d_in[4];
    const float* b2 = (const float*)d_in[5];
    const float* W3 = (const float*)d_in[6];
    const float* b3 = (const float*)d_in[7];
    float* out = (float*)d_out;

    _Float16* P   = (_Float16*)((char*)d_ws + 256);        // 51.2 MB
    _Float16* W1f = P + (size_t)N_NODES * 256;             // 64 KB
    int*      tks = (int*)(W1f + 4096 * 8);                // 2 ints (tk1, tk2)

    k0_w1f<<<16, 256, 0, stream>>>(W1, W1f, tks);
    k1_node_linear<<<768, 256, 0, stream>>>(x, W1f, P, &tks[0]);
    k2_edge_mlp<<<768, 256, 0, stream>>>(P, ei, b1, W2, b2, W3, b3, out, &tks[1]);
}

// Round 12
// 191.652 us; speedup vs baseline: 1.9794x; 1.4464x over previous
//
#include <hip/hip_runtime.h>

#define N_NODES 100000
#define N_EDGES 600000
#define NT1 1563    // k1 node tiles of 64
#define NT2 9375    // k2 edge tiles of 64 (600000 = 9375*64 exactly)
#define LDH 136     // padded row stride (f16 elems), 16B-aligned rows
typedef _Float16 f16x8 __attribute__((ext_vector_type(8)));
typedef __attribute__((ext_vector_type(4))) float f32x4;

__device__ __forceinline__ float elu_f(float v) {
    return v > 0.0f ? v : (__expf(v) - 1.0f);
}

// k0: build W1f (4096 frags, 64KB) for k1 and W2f (2048 frags, 32KB) for k2,
// both in MFMA-fragment order. One-time strided gather here converts every
// per-block weight preload into coalesced dwordx4 (the strided scalar-load
// storm was measured worth ~3us on k1 in r8; k2's W2 preamble is the same
// pattern at half size). 24 blocks: 16 for W1f, 8 for W2f.
extern "C" __global__ __launch_bounds__(256)
void k0_wf(const float* __restrict__ W1, const float* __restrict__ W2,
           _Float16* __restrict__ W1f, _Float16* __restrict__ W2f) {
    const int t = threadIdx.x;
    const int id = blockIdx.x * 256 + t;
    if (id < 4096) {
        // W1f: frag id = (w*16 + half*8 + c*4 + ks), col = w*32+c*16+ln,
        // k = half*128 + ks*32 + kg*8 + j.   [r8, verified]
        const int lane = id & 63, f = id >> 6;
        const int ks = f & 3, c = (f >> 2) & 1, half = (f >> 3) & 1, w = f >> 4;
        const int ln = lane & 15, kg = lane >> 4;
        const int col = w * 32 + c * 16 + ln;
        f16x8 v;
#pragma unroll
        for (int j = 0; j < 8; ++j)
            v[j] = (_Float16)W1[(half * 128 + ks * 32 + kg * 8 + j) * 128 + col];
        *(f16x8*)(W1f + (size_t)id * 8) = v;
    } else {
        // W2f: frag id = (w*8 + c*4 + ks), col = w*32+c*16+ln,
        // k = ks*32 + kg*8 + j.  (index math verbatim from the k2 preamble
        // loop it replaces.)
        const int id2 = id - 4096;
        if (id2 < 2048) {
            const int lane = id2 & 63, f = id2 >> 6;
            const int ks = f & 3, c = (f >> 2) & 1, w = f >> 3;
            const int ln = lane & 15, kg = lane >> 4;
            const int col = w * 32 + c * 16 + ln;
            f16x8 v;
#pragma unroll
            for (int j = 0; j < 8; ++j)
                v[j] = (_Float16)W2[(ks * 32 + kg * 8 + j) * 128 + col];
            *(f16x8*)(W2f + (size_t)id2 * 8) = v;
        }
    }
}

// k1: byte-identical to r8 (session best). Static stride-768 tiles,
// W1f coalesced preload, 6-barrier bounce epilogue.
extern "C" __global__ __launch_bounds__(256, 3)
void k1_node_linear(const float* __restrict__ x, const _Float16* __restrict__ W1f,
                    _Float16* __restrict__ P) {
    __shared__ __align__(16) _Float16 sX[64 * LDH];   // 17.4 KB

    const int t = threadIdx.x;
    const int w = t >> 6, lane = t & 63;
    const int ln = lane & 15, kg = lane >> 4;
    const int le = t >> 2;        // staging/store row 0..63
    const int q  = t & 3;         // 32-col chunk 0..3

    f16x8 bf[2][2][4];
#pragma unroll
    for (int half = 0; half < 2; ++half)
#pragma unroll
        for (int c = 0; c < 2; ++c)
#pragma unroll
            for (int ks = 0; ks < 4; ++ks)
                bf[half][c][ks] = *(const f16x8*)(
                    W1f + (size_t)((w * 16 + half * 8 + c * 4 + ks) * 64 + lane) * 8);

    for (int tile = blockIdx.x; tile < NT1; tile += gridDim.x) {
        const int n0 = tile * 64;
        __syncthreads();   // previous tile's epilogue reads of sX done

        {
            int n = n0 + le;
#pragma unroll
            for (int i = 0; i < 4; ++i) {
                float4 a0 = make_float4(0.f, 0.f, 0.f, 0.f), a1 = a0;
                if (n < N_NODES) {
                    const float* p = x + (size_t)n * 128 + q * 32 + i * 8;
                    a0 = *(const float4*)p; a1 = *(const float4*)(p + 4);
                }
                f16x8 vh;
                vh[0] = (_Float16)a0.x; vh[1] = (_Float16)a0.y;
                vh[2] = (_Float16)a0.z; vh[3] = (_Float16)a0.w;
                vh[4] = (_Float16)a1.x; vh[5] = (_Float16)a1.y;
                vh[6] = (_Float16)a1.z; vh[7] = (_Float16)a1.w;
                *(f16x8*)(&sX[le * LDH + q * 32 + i * 8]) = vh;
            }
        }
        __syncthreads();

        f32x4 acc[2][4][2];
#pragma unroll
        for (int half = 0; half < 2; ++half)
#pragma unroll
            for (int rt = 0; rt < 4; ++rt)
#pragma unroll
                for (int c = 0; c < 2; ++c) acc[half][rt][c] = (f32x4){0.f, 0.f, 0.f, 0.f};

#pragma unroll
        for (int ks = 0; ks < 4; ++ks) {
#pragma unroll
            for (int rt = 0; rt < 4; ++rt) {
                f16x8 a = *(const f16x8*)(&sX[(rt * 16 + ln) * LDH + ks * 32 + kg * 8]);
#pragma unroll
                for (int half = 0; half < 2; ++half)
#pragma unroll
                    for (int c = 0; c < 2; ++c)
                        acc[half][rt][c] = __builtin_amdgcn_mfma_f32_16x16x32_f16(
                            a, bf[half][c][ks], acc[half][rt][c], 0, 0, 0);
            }
        }

#pragma unroll
        for (int half = 0; half < 2; ++half) {
            __syncthreads();
#pragma unroll
            for (int rt = 0; rt < 4; ++rt)
#pragma unroll
                for (int c = 0; c < 2; ++c) {
                    int col = w * 32 + c * 16 + ln;
#pragma unroll
                    for (int reg = 0; reg < 4; ++reg) {
                        int row = rt * 16 + kg * 4 + reg;   // C-layout [m89/m91]
                        sX[row * LDH + col] = (_Float16)acc[half][rt][c][reg];
                    }
                }
            __syncthreads();
            int n = n0 + le;
            if (n < N_NODES) {
                _Float16* dst = P + (size_t)n * 256 + half * 128 + q * 32;
                const _Float16* srcp = &sX[le * LDH + q * 32];
#pragma unroll
                for (int i = 0; i < 4; ++i)
                    *(f16x8*)(dst + i * 8) = *(const f16x8*)(srcp + i * 8);
            }
        }
    }
}

// k2: r8's proven 85us body, UNTOUCHED except the W2 preamble now reads W2f
// coalesced (8 dwordx4/thread instead of 64 strided scalar loads/thread).
// Main loop byte-identical: depth-1 register gather, 1 barrier/tile,
// 3 blocks/CU, static stride-768 tiles.
extern "C" __global__ __launch_bounds__(256, 3)
void k2_edge_mlp(const _Float16* __restrict__ P, const void* __restrict__ eiv,
                 const float* __restrict__ b1, const _Float16* __restrict__ W2f,
                 const float* __restrict__ b2, const float* __restrict__ W3,
                 const float* __restrict__ b3, float* __restrict__ out) {
    __shared__ __align__(16) _Float16 sH[2][64 * LDH];   // 34.8 KB
    __shared__ float sPart[2][4][64];                    // 2 KB
    __shared__ int sFlag;

    const int t = threadIdx.x;
    const int w = t >> 6, lane = t & 63;
    const int ln = lane & 15, kg = lane >> 4;
    const int row = t >> 2;          // staging row 0..63
    const int kc0 = (t & 3) * 4;     // staging k-chunk base (of 16 chunks/row)
    const float b3v = b3[0];
    const int stride = gridDim.x;

    if (t < 64) {
        unsigned v = ((const unsigned*)eiv)[2 * t + 1];
        unsigned long long bm = __ballot(v == 0u);
        if (t == 0) sFlag = (bm == ~0ull) ? 1 : 0;
    }

    f16x8 b1f[4];
#pragma unroll
    for (int i = 0; i < 4; ++i)
#pragma unroll
        for (int j = 0; j < 8; ++j) b1f[i][j] = (_Float16)b1[(kc0 + i) * 8 + j];

    float w3v[2], b2v[2];
#pragma unroll
    for (int c = 0; c < 2; ++c) {
        int col = w * 32 + c * 16 + ln;
        w3v[c] = W3[col]; b2v[c] = b2[col];
    }

    f16x8 bfw[2][4];
#pragma unroll
    for (int c = 0; c < 2; ++c)
#pragma unroll
        for (int ks = 0; ks < 4; ++ks)
            bfw[c][ks] = *(const f16x8*)(
                W2f + (size_t)((w * 8 + c * 4 + ks) * 64 + lane) * 8);

    __syncthreads();
    const int mode64 = sFlag;

    const int tile0 = blockIdx.x;   // 768 <= NT2 always

    int se_nx, ge_nx;
    {
        int e = tile0 * 64 + row;
        if (mode64) {
            se_nx = (int)((const long long*)eiv)[e];
            ge_nx = (int)((const long long*)eiv)[N_EDGES + e];
        } else {
            se_nx = ((const int*)eiv)[e];
            ge_nx = ((const int*)eiv)[N_EDGES + e];
        }
    }
    {
        const _Float16* pa = P + (size_t)se_nx * 256 + kc0 * 8;
        const _Float16* pb = P + (size_t)ge_nx * 256 + 128 + kc0 * 8;
        f16x8 Ga[4], Gb[4];
#pragma unroll
        for (int i = 0; i < 4; ++i) {
            Ga[i] = *(const f16x8*)(pa + i * 8);
            Gb[i] = *(const f16x8*)(pb + i * 8);
        }
#pragma unroll
        for (int i = 0; i < 4; ++i) {
            f16x8 s = Ga[i] + Gb[i] + b1f[i];   // packed f16 adds
            f16x8 vh;
#pragma unroll
            for (int j = 0; j < 8; ++j) {
                _Float16 sv = s[j];
                vh[j] = (sv > (_Float16)0) ? sv
                        : (_Float16)(__expf((float)sv) - 1.0f);
            }
            *(f16x8*)(&sH[0][row * LDH + (kc0 + i) * 8]) = vh;
        }
    }
    {
        int t1 = tile0 + stride;
        int t1c = (t1 < NT2) ? t1 : tile0;
        int e = t1c * 64 + row;
        if (mode64) {
            se_nx = (int)((const long long*)eiv)[e];
            ge_nx = (int)((const long long*)eiv)[N_EDGES + e];
        } else {
            se_nx = ((const int*)eiv)[e];
            ge_nx = ((const int*)eiv)[N_EDGES + e];
        }
    }
    __syncthreads();   // sH[0] ready

    int p = 0;
    int prevE0 = -1;
    for (int tile = tile0; tile < NT2; tile += stride) {
        const int nt = tile + stride;
        const int ntc = (nt < NT2) ? nt : tile;

        // (1) Issue gathers for tile nt.
        const _Float16* pa = P + (size_t)se_nx * 256 + kc0 * 8;
        const _Float16* pb = P + (size_t)ge_nx * 256 + 128 + kc0 * 8;
        f16x8 Ga[4], Gb[4];
#pragma unroll
        for (int i = 0; i < 4; ++i) {
            Ga[i] = *(const f16x8*)(pa + i * 8);
            Gb[i] = *(const f16x8*)(pb + i * 8);
        }

        // (1b) Indices for tile nt+stride.
        {
            int n2 = nt + stride;
            int n2c = (n2 < NT2) ? n2 : ntc;
            int e = n2c * 64 + row;
            if (mode64) {
                se_nx = (int)((const long long*)eiv)[e];
                ge_nx = (int)((const long long*)eiv)[N_EDGES + e];
            } else {
                se_nx = ((const int*)eiv)[e];
                ge_nx = ((const int*)eiv)[N_EDGES + e];
            }
        }

        // (2) Out-write for the previous tile.
        if (prevE0 >= 0 && t < 64)
            out[prevE0 + t] = sPart[p ^ 1][0][t] + sPart[p ^ 1][1][t] +
                              sPart[p ^ 1][2][t] + sPart[p ^ 1][3][t] + b3v;

        // (3) MFMA on sH[p] + fused layer 3 -> sPart[p].
        f32x4 acc[4][2];
#pragma unroll
        for (int rt = 0; rt < 4; ++rt)
#pragma unroll
            for (int c = 0; c < 2; ++c) acc[rt][c] = (f32x4){0.f, 0.f, 0.f, 0.f};

#pragma unroll
        for (int ks = 0; ks < 4; ++ks) {
#pragma unroll
            for (int rt = 0; rt < 4; ++rt) {
                f16x8 a = *(const f16x8*)(&sH[p][(rt * 16 + ln) * LDH + ks * 32 + kg * 8]);
#pragma unroll
                for (int c = 0; c < 2; ++c)
                    acc[rt][c] = __builtin_amdgcn_mfma_f32_16x16x32_f16(a, bfw[c][ks], acc[rt][c], 0, 0, 0);
            }
        }

#pragma unroll
        for (int rt = 0; rt < 4; ++rt) {
            float pr[4] = {0.f, 0.f, 0.f, 0.f};
#pragma unroll
            for (int c = 0; c < 2; ++c) {
#pragma unroll
                for (int reg = 0; reg < 4; ++reg)
                    pr[reg] += elu_f(acc[rt][c][reg] + b2v[c]) * w3v[c];
            }
#pragma unroll
            for (int m = 1; m < 16; m <<= 1)
#pragma unroll
                for (int reg = 0; reg < 4; ++reg) pr[reg] += __shfl_xor(pr[reg], m, 64);
            if (ln == 0) {
#pragma unroll
                for (int reg = 0; reg < 4; ++reg)
                    sPart[p][w][rt * 16 + kg * 4 + reg] = pr[reg];
            }
        }

        // (4) Combine gathered tile nt -> sH[p^1] (packed f16 math).
#pragma unroll
        for (int i = 0; i < 4; ++i) {
            f16x8 s = Ga[i] + Gb[i] + b1f[i];   // v_pk_add_f16
            f16x8 vh;
#pragma unroll
            for (int j = 0; j < 8; ++j) {
                _Float16 sv = s[j];
                vh[j] = (sv > (_Float16)0) ? sv
                        : (_Float16)(__expf((float)sv) - 1.0f);
            }
            *(f16x8*)(&sH[p ^ 1][row * LDH + (kc0 + i) * 8]) = vh;
        }

        prevE0 = tile * 64;
        __syncthreads();   // the ONLY per-tile barrier
        p ^= 1;
    }

    if (prevE0 >= 0 && t < 64)
        out[prevE0 + t] = sPart[p ^ 1][0][t] + sPart[p ^ 1][1][t] +
                          sPart[p ^ 1][2][t] + sPart[p ^ 1][3][t] + b3v;
}

extern "C" void kernel_launch(void* const* d_in, const int* in_sizes, int n_in,
                              void* d_out, int out_size, void* d_ws, size_t ws_size,
                              hipStream_t stream) {
    const float* x  = (const float*)d_in[0];
    const void*  ei = d_in[1];
    const float* W1 = (const float*)d_in[2];
    const float* b1 = (const float*)d_in[3];
    const float* W2 = (const float*)d_in[4];
    const float* b2 = (const float*)d_in[5];
    const float* W3 = (const float*)d_in[6];
    const float* b3 = (const float*)d_in[7];
    float* out = (float*)d_out;

    _Float16* P   = (_Float16*)((char*)d_ws + 256);        // 51.2 MB
    _Float16* W1f = P + (size_t)N_NODES * 256;             // 64 KB
    _Float16* W2f = W1f + 4096 * 8;                        // 32 KB

    k0_wf<<<24, 256, 0, stream>>>(W1, W2, W1f, W2f);
    k1_node_linear<<<768, 256, 0, stream>>>(x, W1f, P);
    k2_edge_mlp<<<768, 256, 0, stream>>>(P, ei, b1, W2f, b2, W3, b3, out);
}